// Round 3
// baseline (1013.597 us; speedup 1.0000x reference)
//
#include <hip/hip_runtime.h>
#include <hip/hip_fp16.h>

// Problem constants
#define Bc  64
#define Sc  256
#define Icc 256
#define Hh  512
#define HW  1024   // 2*Hh

typedef float f32x2 __attribute__((ext_vector_type(2)));

__device__ __forceinline__ f32x2 splat2(float x) { return (f32x2){x, x}; }

__device__ __forceinline__ float fast_tanh(float x) {
  float e = __expf(2.0f * x);
  return 1.0f - 2.0f * __builtin_amdgcn_rcpf(e + 1.0f);
}

template <typename T>
__device__ __forceinline__ float ldf(const T* p) {
  if constexpr (sizeof(T) == 4) return *p;
  else return __half2float(*p);
}
template <typename T>
__device__ __forceinline__ void stf(T* p, float v) {
  if constexpr (sizeof(T) == 4) *p = v;
  else *p = __float2half(v);
}

// Cross-lane add helpers for the 32-lane (half-wave) all-reduce.
// DPP stages run on the VALU pipe (free vs DS); only xor4/xor16 need DS.
template <int CTRL>
__device__ __forceinline__ float dpp_add(float x) {
  int y = __builtin_amdgcn_update_dpp(0, __float_as_int(x), CTRL, 0xF, 0xF, true);
  return x + __int_as_float(y);
}
template <int XMASK>
__device__ __forceinline__ float swz_add(float x) {
  int y = __builtin_amdgcn_ds_swizzle(__float_as_int(x), (XMASK << 10) | 0x1F);
  return x + __int_as_float(y);
}
// quad_perm(1,0,3,2)=0xB1 (xor1), quad_perm(2,3,0,1)=0x4E (xor2), row_ror:8=0x128 (xor8)

// ---------------- GEMM: I[m][h] = sum_k X[m][k] * W[h][k] ----------------
// M=16384, N=1024, K=256. 128x64 tile, 256 threads, 8x4 per thread.
// Inner product uses f32x2 so the compiler can emit v_pk_fma_f32.
template <typename T>
__global__ __launch_bounds__(256, 2) void gemm_xw(const float* __restrict__ X,
                                                  const float* __restrict__ Wm,
                                                  T* __restrict__ Out) {
  __shared__ float As[16][132];  // [k][m], pad 4
  __shared__ float Bs[16][68];   // [k][n], pad 4
  const int tid = threadIdx.x;
  const int m0 = blockIdx.x << 7;   // 128-tile
  const int n0 = blockIdx.y << 6;   // 64-tile
  const int tx4 = (tid & 15) << 2;  // n quad base
  const int ty4 = (tid >> 4) << 2;  // m quad base (0..60)
  const int lr = tid >> 2;          // 0..63 load row
  const int lk = (tid & 3) << 2;    // k quad

  f32x2 acc2[8][2];
#pragma unroll
  for (int i = 0; i < 8; ++i) {
    acc2[i][0] = (f32x2){0.f, 0.f};
    acc2[i][1] = (f32x2){0.f, 0.f};
  }

  const float* xg0 = X + (size_t)(m0 + lr) * Icc + lk;
  const float* xg1 = X + (size_t)(m0 + 64 + lr) * Icc + lk;
  const float* wg  = Wm + (size_t)(n0 + lr) * Icc + lk;

  for (int k0 = 0; k0 < Icc; k0 += 16) {
    float4 a0 = *(const float4*)(xg0 + k0);
    float4 a1 = *(const float4*)(xg1 + k0);
    float4 bv = *(const float4*)(wg + k0);
    __syncthreads();  // protect previous iter's LDS reads
    As[lk + 0][lr] = a0.x; As[lk + 1][lr] = a0.y;
    As[lk + 2][lr] = a0.z; As[lk + 3][lr] = a0.w;
    As[lk + 0][lr + 64] = a1.x; As[lk + 1][lr + 64] = a1.y;
    As[lk + 2][lr + 64] = a1.z; As[lk + 3][lr + 64] = a1.w;
    Bs[lk + 0][lr] = bv.x; Bs[lk + 1][lr] = bv.y;
    Bs[lk + 2][lr] = bv.z; Bs[lk + 3][lr] = bv.w;
    __syncthreads();
#pragma unroll
    for (int kk = 0; kk < 16; ++kk) {
      float a[8];
      f32x2 b2[2];
      *(float4*)&a[0] = *(const float4*)&As[kk][ty4];
      *(float4*)&a[4] = *(const float4*)&As[kk][ty4 + 64];
      *(float4*)&b2[0] = *(const float4*)&Bs[kk][tx4];
#pragma unroll
      for (int i = 0; i < 8; ++i) {
        f32x2 aa = splat2(a[i]);
        acc2[i][0] += aa * b2[0];
        acc2[i][1] += aa * b2[1];
      }
    }
  }
#pragma unroll
  for (int i = 0; i < 8; ++i) {
    const int mrow = m0 + ((i < 4) ? (ty4 + i) : (64 + ty4 + i - 4));
    T* op = Out + (size_t)mrow * HW + n0 + tx4;
    if constexpr (sizeof(T) == 4) {
      *(float4*)op = make_float4(acc2[i][0].x, acc2[i][0].y, acc2[i][1].x, acc2[i][1].y);
    } else {
      stf(op + 0, acc2[i][0].x); stf(op + 1, acc2[i][0].y);
      stf(op + 2, acc2[i][1].x); stf(op + 3, acc2[i][1].y);
    }
  }
}

// ---------------- k-recurrence kernel ----------------
// Grid (64 batches, 8 h-slices) x 64 threads: one thread per (b,h) chain.
// 512 blocks spread over all CUs; software prefetch depth 4 hides If latency.
// Writes keys (fp32) -- keys IS the k sequence, doubling as k-storage.
constexpr float ALPHA = 0.90483741803595957f;  // exp(-1/10)
constexpr float DT    = 0.95122942450071400f;  // exp(-1/20)
constexpr float OMD   = 0.04877057549928599f;  // 1 - DT
constexpr float LR_   = 0.01f;

template <typename T>
__global__ __launch_bounds__(64, 8) void k_kernel(const T* __restrict__ If,
                                                  float* __restrict__ keys) {
  const int b = blockIdx.x;
  const int h = (blockIdx.y << 6) | threadIdx.x;
  const T* ip = If + (size_t)b * Sc * HW + h;
  float* kp = keys + (size_t)b * Sc * Hh + h;
  float ks = 0.f;
  float f[4];
#pragma unroll
  for (int j = 0; j < 4; ++j) f[j] = ldf(ip + (size_t)j * HW);
  for (int t = 0; t < Sc; t += 4) {
#pragma unroll
    for (int u = 0; u < 4; ++u) {
      float cur = f[u];
      float nxt = (t + u + 4 < Sc) ? ldf(ip + (size_t)(t + u + 4) * HW) : 0.f;
      ks = ALPHA * ks + cur;
      kp[(size_t)(t + u) * Hh] = fast_tanh(ks);
      f[u] = nxt;
    }
  }
}

// ---------------- Scan (barrier-free, LDS-free) ----------------
// Grid (16, 64): blockIdx.y = batch, blockIdx.x = row-block (32 rows).
// 256 threads: ch = tid&31 (col chunk of 16), g = tid>>5 (row group of 4).
// Each thread: mem2[32] (= 4 rows x 16 cols, f32x2 pairs) in VGPRs.
// k loaded from keys (global, L1-broadcast); kt recomputed in-register.
// Row reduction: 32-lane butterfly = 3 DPP adds (VALU) + 2 ds_swizzle (DS).
// v-recurrence computed redundantly per-lane (bitwise identical across lanes).
// NO __syncthreads, NO __shared__ -> waves run free, latency self-hides.
template <typename T>
__global__ __launch_bounds__(256, 4) void scan_kernel(const T* __restrict__ If,
                                                      const float* __restrict__ keys,
                                                      float* __restrict__ mem_out,
                                                      float* __restrict__ vals) {
  const int b = blockIdx.y;
  const int rb = blockIdx.x;
  const int tid = threadIdx.x;
  const int ch = tid & 31;   // col chunk 0..31
  const int g = tid >> 5;    // row group 0..7
  const int r0 = rb << 5;
  const int row0 = r0 + (g << 2);  // first of this thread's 4 rows

  f32x2 mem2[32];  // [i*8+jj]: row row0+i, cols 16*ch + 2*jj, 2*jj+1
#pragma unroll
  for (int j = 0; j < 32; ++j) mem2[j] = (f32x2){0.f, 0.f};
  f32x2 kt2[8];
#pragma unroll
  for (int j = 0; j < 8; ++j) kt2[j] = (f32x2){0.f, 0.f};
  float vs[4] = {0.f, 0.f, 0.f, 0.f};
  float vt[4] = {0.f, 0.f, 0.f, 0.f};

  const T* ibase = If + (size_t)b * Sc * HW + 512 + row0;   // iv source
  const float* kb = keys + (size_t)b * Sc * Hh + (ch << 4); // k source
  float* valsb = vals + (size_t)b * Sc * Hh + row0;

  // preload k quads for t=0
  f32x2 kv2[8];
  {
    const float4* kq = (const float4*)kb;
#pragma unroll
    for (int q = 0; q < 4; ++q) {
      float4 v = kq[q];
      kv2[2 * q + 0] = (f32x2){v.x, v.y};
      kv2[2 * q + 1] = (f32x2){v.z, v.w};
    }
  }

  for (int t = 0; t < Sc; ++t) {
    // ---- phase 2: matvec partials (pk-fma) ----
    f32x2 acc2[4];
#pragma unroll
    for (int i = 0; i < 4; ++i) acc2[i] = (f32x2){0.f, 0.f};
#pragma unroll
    for (int jj = 0; jj < 8; ++jj) {
      f32x2 kv = kv2[jj];
      acc2[0] += mem2[jj] * kv;
      acc2[1] += mem2[8 + jj] * kv;
      acc2[2] += mem2[16 + jj] * kv;
      acc2[3] += mem2[24 + jj] * kv;
    }
    float p[4];
#pragma unroll
    for (int i = 0; i < 4; ++i) p[i] = acc2[i].x + acc2[i].y;

    // ---- kt trace update (last use of kv2 this step) ----
#pragma unroll
    for (int jj = 0; jj < 8; ++jj)
      kt2[jj] = splat2(DT) * kt2[jj] + splat2(OMD) * kv2[jj];

    // ---- prefetch next step's k into the now-free kv2 regs ----
    {
      const int tn = (t + 1 < Sc) ? t + 1 : t;
      const float4* kq = (const float4*)(kb + (size_t)tn * Hh);
#pragma unroll
      for (int q = 0; q < 4; ++q) {
        float4 v = kq[q];
        kv2[2 * q + 0] = (f32x2){v.x, v.y};
        kv2[2 * q + 1] = (f32x2){v.z, v.w};
      }
    }

    // ---- 32-lane all-reduce of p[0..3] over col chunks ----
#pragma unroll
    for (int i = 0; i < 4; ++i) p[i] = dpp_add<0xB1>(p[i]);   // xor1
#pragma unroll
    for (int i = 0; i < 4; ++i) p[i] = dpp_add<0x4E>(p[i]);   // xor2
#pragma unroll
    for (int i = 0; i < 4; ++i) p[i] = swz_add<4>(p[i]);      // xor4
#pragma unroll
    for (int i = 0; i < 4; ++i) p[i] = dpp_add<0x128>(p[i]);  // xor8
#pragma unroll
    for (int i = 0; i < 4; ++i) p[i] = swz_add<16>(p[i]);     // xor16

    // ---- iv load (broadcast within half-wave; L1-served) ----
    float iv[4];
    if constexpr (sizeof(T) == 4) {
      float4 q = *(const float4*)(ibase + (size_t)t * HW);
      iv[0] = q.x; iv[1] = q.y; iv[2] = q.z; iv[3] = q.w;
    } else {
      const __half2* hp = (const __half2*)(ibase + (size_t)t * HW);
      float2 fa = __half22float2(hp[0]);
      float2 fb = __half22float2(hp[1]);
      iv[0] = fa.x; iv[1] = fa.y; iv[2] = fb.x; iv[3] = fb.y;
    }

    // ---- v-recurrence (redundant per-lane, identical across lanes) ----
    float vcur[4];
#pragma unroll
    for (int i = 0; i < 4; ++i) {
      vs[i] = fmaf(ALPHA, vs[i], fmaf(0.2f, p[i], iv[i]));
      vcur[i] = fast_tanh(vs[i]);
      vt[i] = fmaf(DT, vt[i], OMD * vcur[i]);
    }
    if (ch == 0) {
      *(float4*)(valsb + (size_t)t * Hh) =
          make_float4(vcur[0], vcur[1], vcur[2], vcur[3]);
    }

    // ---- phase 4: rank-1 mem update (pk-fma) ----
#pragma unroll
    for (int i = 0; i < 4; ++i) {
      const float a = fmaf(-LR_ * vt[i], vt[i], 1.0f);
      const float c = LR_ * vt[i];
      const f32x2 aa = splat2(a);
      const f32x2 cc = splat2(c);
#pragma unroll
      for (int jj = 0; jj < 8; ++jj)
        mem2[i * 8 + jj] = mem2[i * 8 + jj] * aa + cc * kt2[jj];
    }
  }

  // epilogue: write mem
#pragma unroll
  for (int i = 0; i < 4; ++i) {
    float* mb = mem_out + (size_t)b * Hh * Hh + (size_t)(row0 + i) * Hh + (ch << 4);
#pragma unroll
    for (int q = 0; q < 4; ++q) {
      f32x2 lo = mem2[i * 8 + 2 * q];
      f32x2 hi = mem2[i * 8 + 2 * q + 1];
      *(float4*)(mb + 4 * q) = make_float4(lo.x, lo.y, hi.x, hi.y);
    }
  }
}

extern "C" void kernel_launch(void* const* d_in, const int* in_sizes, int n_in,
                              void* d_out, int out_size, void* d_ws, size_t ws_size,
                              hipStream_t stream) {
  const float* x = (const float*)d_in[0];   // (64,256,256) fp32
  const float* W = (const float*)d_in[1];   // (1024,256) fp32
  float* out = (float*)d_out;
  float* mem_out = out;                          // 16,777,216 floats
  float* keys    = out + 16777216;               //  8,388,608 floats
  float* vals    = out + 25165824;               //  8,388,608 floats

  const dim3 gemm_grid(128, 16), gemm_blk(256);
  const dim3 k_grid(64, 8),      k_blk(64);
  const dim3 scan_grid(16, 64),  scan_blk(256);
  const size_t i_elems = (size_t)Bc * Sc * HW;   // 16,777,216

  if (ws_size >= i_elems * sizeof(float)) {
    float* If = (float*)d_ws;
    gemm_xw<float><<<gemm_grid, gemm_blk, 0, stream>>>(x, W, If);
    k_kernel<float><<<k_grid, k_blk, 0, stream>>>(If, keys);
    scan_kernel<float><<<scan_grid, scan_blk, 0, stream>>>(If, keys, mem_out, vals);
  } else {
    __half* If = (__half*)d_ws;
    gemm_xw<__half><<<gemm_grid, gemm_blk, 0, stream>>>(x, W, If);
    k_kernel<__half><<<k_grid, k_blk, 0, stream>>>(If, keys);
    scan_kernel<__half><<<scan_grid, scan_blk, 0, stream>>>(If, keys, mem_out, vals);
  }
}

// Round 4
// 722.919 us; speedup vs baseline: 1.4021x; 1.4021x over previous
//
#include <hip/hip_runtime.h>
#include <hip/hip_fp16.h>

// Problem constants
#define Bc  64
#define Sc  256
#define Icc 256
#define Hh  512
#define HW  1024   // 2*Hh

typedef float f32x2 __attribute__((ext_vector_type(2)));

__device__ __forceinline__ f32x2 splat2(float x) { return (f32x2){x, x}; }

__device__ __forceinline__ float fast_tanh(float x) {
  float e = __expf(2.0f * x);
  return 1.0f - 2.0f * __builtin_amdgcn_rcpf(e + 1.0f);
}

template <typename T>
__device__ __forceinline__ float ldf(const T* p) {
  if constexpr (sizeof(T) == 4) return *p;
  else return __half2float(*p);
}
template <typename T>
__device__ __forceinline__ void stf(T* p, float v) {
  if constexpr (sizeof(T) == 4) *p = v;
  else *p = __float2half(v);
}

// Cross-lane add helpers for the 32-lane (half-wave) all-reduce.
// DPP stages run on the VALU pipe; only xor4/xor16 need DS (ds_swizzle).
// Verified passing in round 3.
template <int CTRL>
__device__ __forceinline__ float dpp_add(float x) {
  int y = __builtin_amdgcn_update_dpp(0, __float_as_int(x), CTRL, 0xF, 0xF, true);
  return x + __int_as_float(y);
}
template <int XMASK>
__device__ __forceinline__ float swz_add(float x) {
  int y = __builtin_amdgcn_ds_swizzle(__float_as_int(x), (XMASK << 10) | 0x1F);
  return x + __int_as_float(y);
}
// quad_perm(1,0,3,2)=0xB1 (xor1), quad_perm(2,3,0,1)=0x4E (xor2), row_ror:8=0x128 (xor8)

constexpr float ALPHA = 0.90483741803595957f;  // exp(-1/10)
constexpr float DT    = 0.95122942450071400f;  // exp(-1/20)
constexpr float OMD   = 0.04877057549928599f;  // 1 - DT
constexpr float LR_   = 0.01f;

// ---------------- GEMM: I[m][h] = sum_k X[m][k] * W[h][k] ----------------
// M=16384, N=1024, K=256. 128x64 tile, 256 threads, 8x4 per thread.
// (unchanged from round 3 -- scan is this round's experiment)
template <typename T>
__global__ __launch_bounds__(256, 2) void gemm_xw(const float* __restrict__ X,
                                                  const float* __restrict__ Wm,
                                                  T* __restrict__ Out) {
  __shared__ float As[16][132];  // [k][m], pad 4
  __shared__ float Bs[16][68];   // [k][n], pad 4
  const int tid = threadIdx.x;
  const int m0 = blockIdx.x << 7;
  const int n0 = blockIdx.y << 6;
  const int tx4 = (tid & 15) << 2;
  const int ty4 = (tid >> 4) << 2;
  const int lr = tid >> 2;
  const int lk = (tid & 3) << 2;

  f32x2 acc2[8][2];
#pragma unroll
  for (int i = 0; i < 8; ++i) {
    acc2[i][0] = (f32x2){0.f, 0.f};
    acc2[i][1] = (f32x2){0.f, 0.f};
  }

  const float* xg0 = X + (size_t)(m0 + lr) * Icc + lk;
  const float* xg1 = X + (size_t)(m0 + 64 + lr) * Icc + lk;
  const float* wg  = Wm + (size_t)(n0 + lr) * Icc + lk;

  for (int k0 = 0; k0 < Icc; k0 += 16) {
    float4 a0 = *(const float4*)(xg0 + k0);
    float4 a1 = *(const float4*)(xg1 + k0);
    float4 bv = *(const float4*)(wg + k0);
    __syncthreads();
    As[lk + 0][lr] = a0.x; As[lk + 1][lr] = a0.y;
    As[lk + 2][lr] = a0.z; As[lk + 3][lr] = a0.w;
    As[lk + 0][lr + 64] = a1.x; As[lk + 1][lr + 64] = a1.y;
    As[lk + 2][lr + 64] = a1.z; As[lk + 3][lr + 64] = a1.w;
    Bs[lk + 0][lr] = bv.x; Bs[lk + 1][lr] = bv.y;
    Bs[lk + 2][lr] = bv.z; Bs[lk + 3][lr] = bv.w;
    __syncthreads();
#pragma unroll
    for (int kk = 0; kk < 16; ++kk) {
      float a[8];
      f32x2 b2[2];
      *(float4*)&a[0] = *(const float4*)&As[kk][ty4];
      *(float4*)&a[4] = *(const float4*)&As[kk][ty4 + 64];
      *(float4*)&b2[0] = *(const float4*)&Bs[kk][tx4];
#pragma unroll
      for (int i = 0; i < 8; ++i) {
        f32x2 aa = splat2(a[i]);
        acc2[i][0] += aa * b2[0];
        acc2[i][1] += aa * b2[1];
      }
    }
  }
#pragma unroll
  for (int i = 0; i < 8; ++i) {
    const int mrow = m0 + ((i < 4) ? (ty4 + i) : (64 + ty4 + i - 4));
    T* op = Out + (size_t)mrow * HW + n0 + tx4;
    if constexpr (sizeof(T) == 4) {
      *(float4*)op = make_float4(acc2[i][0].x, acc2[i][0].y, acc2[i][1].x, acc2[i][1].y);
    } else {
      stf(op + 0, acc2[i][0].x); stf(op + 1, acc2[i][0].y);
      stf(op + 2, acc2[i][1].x); stf(op + 3, acc2[i][1].y);
    }
  }
}

// ---------------- Scan (hybrid: LDS k-staging + in-wave butterfly) ----------
// Grid (16, 64): blockIdx.y = batch, blockIdx.x = row-block (32 rows).
// 256 threads: ch = tid&31 (col chunk of 16), g = tid>>5 (row group of 4).
// Each half-wave holds all 32 chunk-partials of its 4 rows -> butterfly
// reduce (3 DPP adds on VALU + 2 ds_swizzle), no reduction LDS/barriers.
// k/kt computed in-kernel (2 chains/thread), staged in LDS double buffer
// with chunk-stride-20 layout (uniform 4 accesses/bank on b128 reads = BW
// floor; b64 writes <=2-way = free). ONE barrier per step keeps waves in
// lockstep so vals/keys lines merge in L2 (round-0-verified: zero write
// amplification). iv/ik prefetched one step ahead in registers.
template <typename T>
__global__ __launch_bounds__(256, 4) void scan_kernel(const T* __restrict__ If,
                                                      float* __restrict__ mem_out,
                                                      float* __restrict__ keys,
                                                      float* __restrict__ vals) {
  const int b = blockIdx.y;
  const int rb = blockIdx.x;
  const int tid = threadIdx.x;
  const int ch = tid & 31;   // col chunk 0..31
  const int g = tid >> 5;    // row group 0..7
  const int r0 = rb << 5;
  const int row0 = r0 + (g << 2);  // first of this thread's 4 rows

  __shared__ float k_s[2][640];   // 32 chunks x 20 floats, double-buffered
  __shared__ float kt_s[2][640];

  f32x2 mem2[32];  // [i*8+jj]: row row0+i, cols 16*ch + 2*jj, 2*jj+1
#pragma unroll
  for (int j = 0; j < 32; ++j) mem2[j] = (f32x2){0.f, 0.f};
  float kss0 = 0.f, kss1 = 0.f, ktr0 = 0.f, ktr1 = 0.f;  // k-chain state
  float vs[4] = {0.f, 0.f, 0.f, 0.f};
  float vt[4] = {0.f, 0.f, 0.f, 0.f};

  const int h0 = 2 * tid;                                  // owned channels
  const int sidx = (tid >> 3) * 20 + (h0 & 15);            // staging index
  const T* ikp = If + (size_t)b * Sc * HW + h0;            // ik source
  const T* ivp = If + (size_t)b * Sc * HW + 512 + row0;    // iv source
  float* keysb = keys + (size_t)b * Sc * Hh;
  float* valsb = vals + (size_t)b * Sc * Hh + row0;

  // prefetch t=0 inputs
  float ik0, ik1, iv[4];
  {
    if constexpr (sizeof(T) == 4) {
      float2 v2 = *(const float2*)ikp;
      ik0 = v2.x; ik1 = v2.y;
      float4 q = *(const float4*)ivp;
      iv[0] = q.x; iv[1] = q.y; iv[2] = q.z; iv[3] = q.w;
    } else {
      float2 v2 = __half22float2(*(const __half2*)ikp);
      ik0 = v2.x; ik1 = v2.y;
      const __half2* hp = (const __half2*)ivp;
      float2 fa = __half22float2(hp[0]), fb = __half22float2(hp[1]);
      iv[0] = fa.x; iv[1] = fa.y; iv[2] = fb.x; iv[3] = fb.y;
    }
  }

  for (int t = 0; t < Sc; ++t) {
    const int buf = t & 1;

    // ---- phase 1: k-chain update for own 2 channels, stage to LDS ----
    const float cik0 = ik0, cik1 = ik1;
    float civ0 = iv[0], civ1 = iv[1], civ2 = iv[2], civ3 = iv[3];
    // prefetch t+1 (clamped; issued early so latency hides under the step)
    {
      const size_t tn = (size_t)((t + 1 < Sc) ? t + 1 : t) * HW;
      if constexpr (sizeof(T) == 4) {
        float2 v2 = *(const float2*)(ikp + tn);
        ik0 = v2.x; ik1 = v2.y;
        float4 q = *(const float4*)(ivp + tn);
        iv[0] = q.x; iv[1] = q.y; iv[2] = q.z; iv[3] = q.w;
      } else {
        float2 v2 = __half22float2(*(const __half2*)(ikp + tn));
        ik0 = v2.x; ik1 = v2.y;
        const __half2* hp = (const __half2*)(ivp + tn);
        float2 fa = __half22float2(hp[0]), fb = __half22float2(hp[1]);
        iv[0] = fa.x; iv[1] = fa.y; iv[2] = fb.x; iv[3] = fb.y;
      }
    }
    kss0 = ALPHA * kss0 + cik0;
    kss1 = ALPHA * kss1 + cik1;
    float k0 = fast_tanh(kss0);
    float k1 = fast_tanh(kss1);
    ktr0 = DT * ktr0 + OMD * k0;
    ktr1 = DT * ktr1 + OMD * k1;
    *(float2*)&k_s[buf][sidx]  = make_float2(k0, k1);
    *(float2*)&kt_s[buf][sidx] = make_float2(ktr0, ktr1);
    if (rb == 0) {
      *(float2*)&keysb[(size_t)t * Hh + h0] = make_float2(k0, k1);
    }
    __syncthreads();  // the only barrier per step

    // ---- phase 2: matvec partials over this thread's 4x16 patch ----
    f32x2 acc2[4];
#pragma unroll
    for (int i = 0; i < 4; ++i) acc2[i] = (f32x2){0.f, 0.f};
    {
      const float4* kc = (const float4*)&k_s[buf][ch * 20];
#pragma unroll
      for (int q = 0; q < 4; ++q) {
        float4 kq = kc[q];
        f32x2 kv0 = (f32x2){kq.x, kq.y};
        f32x2 kv1 = (f32x2){kq.z, kq.w};
        const int jj = 2 * q;
        acc2[0] += mem2[jj] * kv0 + mem2[jj + 1] * kv1;
        acc2[1] += mem2[8 + jj] * kv0 + mem2[8 + jj + 1] * kv1;
        acc2[2] += mem2[16 + jj] * kv0 + mem2[16 + jj + 1] * kv1;
        acc2[3] += mem2[24 + jj] * kv0 + mem2[24 + jj + 1] * kv1;
      }
    }
    float p[4];
#pragma unroll
    for (int i = 0; i < 4; ++i) p[i] = acc2[i].x + acc2[i].y;

    // ---- 32-lane butterfly all-reduce over col chunks ----
#pragma unroll
    for (int i = 0; i < 4; ++i) p[i] = dpp_add<0xB1>(p[i]);   // xor1
#pragma unroll
    for (int i = 0; i < 4; ++i) p[i] = dpp_add<0x4E>(p[i]);   // xor2
#pragma unroll
    for (int i = 0; i < 4; ++i) p[i] = swz_add<4>(p[i]);      // xor4
#pragma unroll
    for (int i = 0; i < 4; ++i) p[i] = dpp_add<0x128>(p[i]);  // xor8
#pragma unroll
    for (int i = 0; i < 4; ++i) p[i] = swz_add<16>(p[i]);     // xor16

    // ---- phase 3: v-recurrence, redundant per-lane (identical values) ----
    float a[4], c[4];
    {
      float vcur[4];
      vs[0] = fmaf(ALPHA, vs[0], fmaf(0.2f, p[0], civ0));
      vs[1] = fmaf(ALPHA, vs[1], fmaf(0.2f, p[1], civ1));
      vs[2] = fmaf(ALPHA, vs[2], fmaf(0.2f, p[2], civ2));
      vs[3] = fmaf(ALPHA, vs[3], fmaf(0.2f, p[3], civ3));
#pragma unroll
      for (int i = 0; i < 4; ++i) {
        vcur[i] = fast_tanh(vs[i]);
        vt[i] = fmaf(DT, vt[i], OMD * vcur[i]);
        a[i] = fmaf(-LR_ * vt[i], vt[i], 1.0f);
        c[i] = LR_ * vt[i];
      }
      if (ch == 0) {
        *(float4*)(valsb + (size_t)t * Hh) =
            make_float4(vcur[0], vcur[1], vcur[2], vcur[3]);
      }
    }

    // ---- phase 4: rank-1 mem update (kt from LDS, q-outer to cap regs) ----
    {
      const float4* ktc = (const float4*)&kt_s[buf][ch * 20];
#pragma unroll
      for (int q = 0; q < 4; ++q) {
        float4 kq = ktc[q];
        f32x2 kv0 = (f32x2){kq.x, kq.y};
        f32x2 kv1 = (f32x2){kq.z, kq.w};
        const int jj = 2 * q;
#pragma unroll
        for (int i = 0; i < 4; ++i) {
          const f32x2 aa = splat2(a[i]);
          mem2[i * 8 + jj]     = mem2[i * 8 + jj]     * aa + splat2(c[i]) * kv0;
          mem2[i * 8 + jj + 1] = mem2[i * 8 + jj + 1] * aa + splat2(c[i]) * kv1;
        }
      }
    }
    // no trailing barrier: next step writes buf^1; its B1 separates this
    // step's reads of buf from step t+2's writes of buf.
  }

  // epilogue: write mem (once)
#pragma unroll
  for (int i = 0; i < 4; ++i) {
    float* mb = mem_out + (size_t)b * Hh * Hh + (size_t)(row0 + i) * Hh + (ch << 4);
#pragma unroll
    for (int q = 0; q < 4; ++q) {
      f32x2 lo = mem2[i * 8 + 2 * q];
      f32x2 hi = mem2[i * 8 + 2 * q + 1];
      *(float4*)(mb + 4 * q) = make_float4(lo.x, lo.y, hi.x, hi.y);
    }
  }
}

extern "C" void kernel_launch(void* const* d_in, const int* in_sizes, int n_in,
                              void* d_out, int out_size, void* d_ws, size_t ws_size,
                              hipStream_t stream) {
  const float* x = (const float*)d_in[0];   // (64,256,256) fp32
  const float* W = (const float*)d_in[1];   // (1024,256) fp32
  float* out = (float*)d_out;
  float* mem_out = out;                          // 16,777,216 floats
  float* keys    = out + 16777216;               //  8,388,608 floats
  float* vals    = out + 25165824;               //  8,388,608 floats

  const dim3 gemm_grid(128, 16), gemm_blk(256);
  const dim3 scan_grid(16, 64),  scan_blk(256);
  const size_t i_elems = (size_t)Bc * Sc * HW;   // 16,777,216

  if (ws_size >= i_elems * sizeof(float)) {
    float* If = (float*)d_ws;
    gemm_xw<float><<<gemm_grid, gemm_blk, 0, stream>>>(x, W, If);
    scan_kernel<float><<<scan_grid, scan_blk, 0, stream>>>(If, mem_out, keys, vals);
  } else {
    __half* If = (__half*)d_ws;
    gemm_xw<__half><<<gemm_grid, gemm_blk, 0, stream>>>(x, W, If);
    scan_kernel<__half><<<scan_grid, scan_blk, 0, stream>>>(If, mem_out, keys, vals);
  }
}

// Round 5
// 656.273 us; speedup vs baseline: 1.5445x; 1.1016x over previous
//
#include <hip/hip_runtime.h>
#include <hip/hip_fp16.h>

// Problem constants
#define Bc  64
#define Sc  256
#define Icc 256
#define Hh  512
#define HW  1024   // 2*Hh

typedef float f32x2 __attribute__((ext_vector_type(2)));

__device__ __forceinline__ f32x2 splat2(float x) { return (f32x2){x, x}; }

__device__ __forceinline__ float fast_tanh(float x) {
  float e = __expf(2.0f * x);
  return 1.0f - 2.0f * __builtin_amdgcn_rcpf(e + 1.0f);
}

template <typename T>
__device__ __forceinline__ float ldf(const T* p) {
  if constexpr (sizeof(T) == 4) return *p;
  else return __half2float(*p);
}
template <typename T>
__device__ __forceinline__ void stf(T* p, float v) {
  if constexpr (sizeof(T) == 4) *p = v;
  else *p = __float2half(v);
}

// Cross-lane helpers (verified passing rounds 3-4).
template <int CTRL>
__device__ __forceinline__ float dpp_mov(float x) {
  return __int_as_float(
      __builtin_amdgcn_update_dpp(0, __float_as_int(x), CTRL, 0xF, 0xF, true));
}
template <int CTRL>
__device__ __forceinline__ float dpp_add(float x) {
  return x + dpp_mov<CTRL>(x);
}
template <int XMASK>
__device__ __forceinline__ float swz_add(float x) {
  int y = __builtin_amdgcn_ds_swizzle(__float_as_int(x), (XMASK << 10) | 0x1F);
  return x + __int_as_float(y);
}
// quad_perm(1,0,3,2)=0xB1 (xor1), quad_perm(2,3,0,1)=0x4E (xor2),
// row_ror:8=0x128 (xor8 within 16), quad bcast i = {0x00,0x55,0xAA,0xFF}

constexpr float ALPHA = 0.90483741803595957f;  // exp(-1/10)
constexpr float DT    = 0.95122942450071400f;  // exp(-1/20)
constexpr float OMD   = 0.04877057549928599f;  // 1 - DT
constexpr float LR_   = 0.01f;

// LDS column map for GEMM fragments: insert 4 floats of pad every 32 so the
// sixteen stride-8 b128 fragment reads per wave spread to 2-way (free).
__device__ __forceinline__ int gpos(int m) { return m + ((m >> 5) << 2); }

// ---------------- GEMM: I[m][h] = sum_k X[m][k] * W[h][k] ----------------
// M=16384, N=1024, K=256. 128x128 tile, 256 threads, 8x8 per thread.
// Global->LDS staging prefetched one K-chunk ahead (issue after barrier,
// consume next iteration) so HBM latency hides under the 16-kk compute.
template <typename T>
__global__ __launch_bounds__(256, 2) void gemm_xw(const float* __restrict__ X,
                                                  const float* __restrict__ Wm,
                                                  T* __restrict__ Out) {
  __shared__ float As[16][140];  // [k][gpos(m)]
  __shared__ float Bs[16][140];  // [k][gpos(n)]
  const int tid = threadIdx.x;
  const int m0 = blockIdx.x << 7;   // 128 X-rows
  const int n0 = blockIdx.y << 7;   // 128 W-rows
  const int tx8 = (tid & 15) << 3;  // n octet base
  const int ty8 = (tid >> 4) << 3;  // m octet base
  const int lr = tid >> 2;          // 0..63 load row
  const int lk = (tid & 3) << 2;    // k quad
  const int plr  = gpos(lr);
  const int plr6 = gpos(lr + 64);
  const int pty  = gpos(ty8);       // octets never straddle a pad boundary
  const int ptx  = gpos(tx8);

  f32x2 acc[8][4];  // 8 m-rows x 8 n-cols (4 f32x2)
#pragma unroll
  for (int i = 0; i < 8; ++i)
#pragma unroll
    for (int j = 0; j < 4; ++j) acc[i][j] = (f32x2){0.f, 0.f};

  const float* xg0 = X + (size_t)(m0 + lr) * Icc + lk;
  const float* xg1 = X + (size_t)(m0 + 64 + lr) * Icc + lk;
  const float* wg0 = Wm + (size_t)(n0 + lr) * Icc + lk;
  const float* wg1 = Wm + (size_t)(n0 + 64 + lr) * Icc + lk;

  float4 a0 = *(const float4*)xg0;
  float4 a1 = *(const float4*)xg1;
  float4 b0 = *(const float4*)wg0;
  float4 b1 = *(const float4*)wg1;

  for (int k0 = 0; k0 < Icc; k0 += 16) {
    __syncthreads();  // protect previous iter's LDS reads
    As[lk + 0][plr] = a0.x; As[lk + 1][plr] = a0.y;
    As[lk + 2][plr] = a0.z; As[lk + 3][plr] = a0.w;
    As[lk + 0][plr6] = a1.x; As[lk + 1][plr6] = a1.y;
    As[lk + 2][plr6] = a1.z; As[lk + 3][plr6] = a1.w;
    Bs[lk + 0][plr] = b0.x; Bs[lk + 1][plr] = b0.y;
    Bs[lk + 2][plr] = b0.z; Bs[lk + 3][plr] = b0.w;
    Bs[lk + 0][plr6] = b1.x; Bs[lk + 1][plr6] = b1.y;
    Bs[lk + 2][plr6] = b1.z; Bs[lk + 3][plr6] = b1.w;
    __syncthreads();
    if (k0 + 16 < Icc) {  // prefetch next chunk; waits at next iter's writes
      a0 = *(const float4*)(xg0 + k0 + 16);
      a1 = *(const float4*)(xg1 + k0 + 16);
      b0 = *(const float4*)(wg0 + k0 + 16);
      b1 = *(const float4*)(wg1 + k0 + 16);
    }
#pragma unroll
    for (int kk = 0; kk < 16; ++kk) {
      float av[8];
      f32x2 bv[4];
      *(float4*)&av[0] = *(const float4*)&As[kk][pty];
      *(float4*)&av[4] = *(const float4*)&As[kk][pty + 4];
      *(float4*)&bv[0] = *(const float4*)&Bs[kk][ptx];
      *(float4*)&bv[2] = *(const float4*)&Bs[kk][ptx + 4];
#pragma unroll
      for (int i = 0; i < 8; ++i) {
        const f32x2 aa = splat2(av[i]);
#pragma unroll
        for (int j = 0; j < 4; ++j) acc[i][j] += aa * bv[j];
      }
    }
  }
#pragma unroll
  for (int i = 0; i < 8; ++i) {
    const int mrow = m0 + ty8 + i;
    T* op = Out + (size_t)mrow * HW + n0 + tx8;
    if constexpr (sizeof(T) == 4) {
      *(float4*)op = make_float4(acc[i][0].x, acc[i][0].y, acc[i][1].x, acc[i][1].y);
      *(float4*)(op + 4) = make_float4(acc[i][2].x, acc[i][2].y, acc[i][3].x, acc[i][3].y);
    } else {
#pragma unroll
      for (int j = 0; j < 4; ++j) {
        stf(op + 2 * j, acc[i][j].x);
        stf(op + 2 * j + 1, acc[i][j].y);
      }
    }
  }
}

// ---------------- Scan (LDS k-staging + reduce-scatter butterfly) ----------
// Grid (16, 64): blockIdx.y = batch, blockIdx.x = row-block (32 rows).
// 256 threads: ch = tid&31 (col chunk of 16), g = tid>>5 (row group of 4).
// Reduction is a reduce-SCATTER: the first two butterfly stages also scatter
// rows across lanes (lane L ends owning the full sum of row L&3), so the
// v-recurrence runs once per row per lane (1 tanh, not 4) and a,c broadcast
// back with quad_perm DPP movs. All 8 lane-copies of a row's sum are
// bitwise identical (commutative-symmetric adds), so chains stay consistent.
// k/kt computed in-kernel (2 chains/thread), staged in LDS double buffer
// (chunk-stride-20 layout). ONE barrier per step keeps waves in lockstep
// (round-4-verified: ideal write bytes). ik/iv prefetched one step ahead.
template <typename T>
__global__ __launch_bounds__(256, 4) void scan_kernel(const T* __restrict__ If,
                                                      float* __restrict__ mem_out,
                                                      float* __restrict__ keys,
                                                      float* __restrict__ vals) {
  const int b = blockIdx.y;
  const int rb = blockIdx.x;
  const int tid = threadIdx.x;
  const int ch = tid & 31;   // col chunk 0..31
  const int g = tid >> 5;    // row group 0..7
  const int r0 = rb << 5;
  const int row0 = r0 + (g << 2);  // first of this thread's 4 rows
  const int ri = ch & 3;           // the row this lane owns after scatter

  __shared__ float k_s[2][640];   // 32 chunks x 20 floats, double-buffered
  __shared__ float kt_s[2][640];

  f32x2 mem2[32];  // [i*8+jj]: row row0+i, cols 16*ch + 2*jj, 2*jj+1
#pragma unroll
  for (int j = 0; j < 32; ++j) mem2[j] = (f32x2){0.f, 0.f};
  float kss0 = 0.f, kss1 = 0.f, ktr0 = 0.f, ktr1 = 0.f;  // k-chain state
  float vs = 0.f, vt = 0.f;                              // own row's v-chain

  const int h0 = 2 * tid;                                  // owned channels
  const int sidx = (tid >> 3) * 20 + (h0 & 15);            // staging index
  const T* ikp = If + (size_t)b * Sc * HW + h0;            // ik source
  const T* ivp = If + (size_t)b * Sc * HW + 512 + row0 + ri;  // own-row iv
  float* keysb = keys + (size_t)b * Sc * Hh;
  float* valsb = vals + (size_t)b * Sc * Hh + row0;

  const bool sb0 = (ch & 1) != 0;  // scatter-stage selects (loop-invariant)
  const bool sb1 = (ch & 2) != 0;

  // prefetch t=0 inputs
  float ik0, ik1, ivc;
  {
    if constexpr (sizeof(T) == 4) {
      float2 v2 = *(const float2*)ikp;
      ik0 = v2.x; ik1 = v2.y;
    } else {
      float2 v2 = __half22float2(*(const __half2*)ikp);
      ik0 = v2.x; ik1 = v2.y;
    }
    ivc = ldf(ivp);
  }

  for (int t = 0; t < Sc; ++t) {
    const int buf = t & 1;

    // ---- phase 1: k-chain update for own 2 channels, stage to LDS ----
    const float cik0 = ik0, cik1 = ik1;
    const float civ = ivc;
    {  // prefetch t+1 (clamped)
      const size_t tn = (size_t)((t + 1 < Sc) ? t + 1 : t) * HW;
      if constexpr (sizeof(T) == 4) {
        float2 v2 = *(const float2*)(ikp + tn);
        ik0 = v2.x; ik1 = v2.y;
      } else {
        float2 v2 = __half22float2(*(const __half2*)(ikp + tn));
        ik0 = v2.x; ik1 = v2.y;
      }
      ivc = ldf(ivp + tn);
    }
    kss0 = ALPHA * kss0 + cik0;
    kss1 = ALPHA * kss1 + cik1;
    float k0 = fast_tanh(kss0);
    float k1 = fast_tanh(kss1);
    ktr0 = DT * ktr0 + OMD * k0;
    ktr1 = DT * ktr1 + OMD * k1;
    *(float2*)&k_s[buf][sidx]  = make_float2(k0, k1);
    *(float2*)&kt_s[buf][sidx] = make_float2(ktr0, ktr1);
    if (rb == 0) {
      *(float2*)&keysb[(size_t)t * Hh + h0] = make_float2(k0, k1);
    }
    __syncthreads();  // the only barrier per step

    // ---- phase 2: matvec partials over this thread's 4x16 patch ----
    f32x2 acc2[4];
#pragma unroll
    for (int i = 0; i < 4; ++i) acc2[i] = (f32x2){0.f, 0.f};
    {
      const float4* kc = (const float4*)&k_s[buf][ch * 20];
#pragma unroll
      for (int q = 0; q < 4; ++q) {
        float4 kq = kc[q];
        f32x2 kv0 = (f32x2){kq.x, kq.y};
        f32x2 kv1 = (f32x2){kq.z, kq.w};
        const int jj = 2 * q;
        acc2[0] += mem2[jj] * kv0 + mem2[jj + 1] * kv1;
        acc2[1] += mem2[8 + jj] * kv0 + mem2[8 + jj + 1] * kv1;
        acc2[2] += mem2[16 + jj] * kv0 + mem2[16 + jj + 1] * kv1;
        acc2[3] += mem2[24 + jj] * kv0 + mem2[24 + jj + 1] * kv1;
      }
    }
    float p0 = acc2[0].x + acc2[0].y;
    float p1 = acc2[1].x + acc2[1].y;
    float p2 = acc2[2].x + acc2[2].y;
    float p3 = acc2[3].x + acc2[3].y;

    // ---- reduce-scatter over 32 chunks; lane L ends with row L&3's sum ----
    // stage xor1: scatter row bit0 by lane bit0
    float x  = sb0 ? p0 : p1;   // value partner needs
    float y  = sb0 ? p2 : p3;
    float o0 = sb0 ? p1 : p0;   // own kept row
    float o1 = sb0 ? p3 : p2;
    float q0 = o0 + dpp_mov<0xB1>(x);   // row (L&1), pair-summed
    float q1 = o1 + dpp_mov<0xB1>(y);   // row (L&1)+2
    // stage xor2: scatter row bit1 by lane bit1
    float x2 = sb1 ? q0 : q1;
    float o2 = sb1 ? q1 : q0;
    float s = o2 + dpp_mov<0x4E>(x2);   // row L&3, quad-summed
    // complete the reduction over remaining lane bits
    s = swz_add<4>(s);
    s = dpp_add<0x128>(s);
    s = swz_add<16>(s);

    // ---- phase 3: v-recurrence for the ONE owned row ----
    vs = fmaf(ALPHA, vs, fmaf(0.2f, s, civ));
    float v = fast_tanh(vs);
    vt = fmaf(DT, vt, OMD * v);
    float a_own = fmaf(-LR_ * vt, vt, 1.0f);
    float c_own = LR_ * vt;
    // broadcast a,c for all 4 rows to every lane (quad_perm bcast)
    float a0 = dpp_mov<0x00>(a_own), a1 = dpp_mov<0x55>(a_own);
    float a2 = dpp_mov<0xAA>(a_own), a3 = dpp_mov<0xFF>(a_own);
    float c0 = dpp_mov<0x00>(c_own), c1 = dpp_mov<0x55>(c_own);
    float c2 = dpp_mov<0xAA>(c_own), c3 = dpp_mov<0xFF>(c_own);
    if (ch < 4) {
      valsb[(size_t)t * Hh + ch] = v;  // lanes 0..3 hold rows 0..3
    }

    // ---- phase 4: rank-1 mem update (kt from LDS) ----
    {
      const float4* ktc = (const float4*)&kt_s[buf][ch * 20];
#pragma unroll
      for (int q = 0; q < 4; ++q) {
        float4 kq = ktc[q];
        f32x2 kv0 = (f32x2){kq.x, kq.y};
        f32x2 kv1 = (f32x2){kq.z, kq.w};
        const int jj = 2 * q;
        mem2[jj]          = mem2[jj]          * splat2(a0) + splat2(c0) * kv0;
        mem2[jj + 1]      = mem2[jj + 1]      * splat2(a0) + splat2(c0) * kv1;
        mem2[8 + jj]      = mem2[8 + jj]      * splat2(a1) + splat2(c1) * kv0;
        mem2[8 + jj + 1]  = mem2[8 + jj + 1]  * splat2(a1) + splat2(c1) * kv1;
        mem2[16 + jj]     = mem2[16 + jj]     * splat2(a2) + splat2(c2) * kv0;
        mem2[16 + jj + 1] = mem2[16 + jj + 1] * splat2(a2) + splat2(c2) * kv1;
        mem2[24 + jj]     = mem2[24 + jj]     * splat2(a3) + splat2(c3) * kv0;
        mem2[24 + jj + 1] = mem2[24 + jj + 1] * splat2(a3) + splat2(c3) * kv1;
      }
    }
    // no trailing barrier: next step writes buf^1; its B1 separates this
    // step's reads of buf from step t+2's writes of buf.
  }

  // epilogue: write mem (once)
#pragma unroll
  for (int i = 0; i < 4; ++i) {
    float* mb = mem_out + (size_t)b * Hh * Hh + (size_t)(row0 + i) * Hh + (ch << 4);
#pragma unroll
    for (int q = 0; q < 4; ++q) {
      f32x2 lo = mem2[i * 8 + 2 * q];
      f32x2 hi = mem2[i * 8 + 2 * q + 1];
      *(float4*)(mb + 4 * q) = make_float4(lo.x, lo.y, hi.x, hi.y);
    }
  }
}

extern "C" void kernel_launch(void* const* d_in, const int* in_sizes, int n_in,
                              void* d_out, int out_size, void* d_ws, size_t ws_size,
                              hipStream_t stream) {
  const float* x = (const float*)d_in[0];   // (64,256,256) fp32
  const float* W = (const float*)d_in[1];   // (1024,256) fp32
  float* out = (float*)d_out;
  float* mem_out = out;                          // 16,777,216 floats
  float* keys    = out + 16777216;               //  8,388,608 floats
  float* vals    = out + 25165824;               //  8,388,608 floats

  const dim3 gemm_grid(128, 8), gemm_blk(256);
  const dim3 scan_grid(16, 64), scan_blk(256);
  const size_t i_elems = (size_t)Bc * Sc * HW;   // 16,777,216

  if (ws_size >= i_elems * sizeof(float)) {
    float* If = (float*)d_ws;
    gemm_xw<float><<<gemm_grid, gemm_blk, 0, stream>>>(x, W, If);
    scan_kernel<float><<<scan_grid, scan_blk, 0, stream>>>(If, mem_out, keys, vals);
  } else {
    __half* If = (__half*)d_ws;
    gemm_xw<__half><<<gemm_grid, gemm_blk, 0, stream>>>(x, W, If);
    scan_kernel<__half><<<scan_grid, scan_blk, 0, stream>>>(If, mem_out, keys, vals);
  }
}

// Round 7
// 557.363 us; speedup vs baseline: 1.8186x; 1.1775x over previous
//
#include <hip/hip_runtime.h>
#include <hip/hip_fp16.h>

// Problem constants
#define Bc  64
#define Sc  256
#define Icc 256
#define Hh  512
#define HW  1024   // 2*Hh

typedef float f32x2 __attribute__((ext_vector_type(2)));

__device__ __forceinline__ f32x2 splat2(float x) { return (f32x2){x, x}; }

__device__ __forceinline__ float fast_tanh(float x) {
  float e = __expf(2.0f * x);
  return 1.0f - 2.0f * __builtin_amdgcn_rcpf(e + 1.0f);
}

template <typename T>
__device__ __forceinline__ float ldf(const T* p) {
  if constexpr (sizeof(T) == 4) return *p;
  else return __half2float(*p);
}
template <typename T>
__device__ __forceinline__ void stf(T* p, float v) {
  if constexpr (sizeof(T) == 4) *p = v;
  else *p = __float2half(v);
}

// Cross-lane helpers (verified passing rounds 3-5).
template <int CTRL>
__device__ __forceinline__ float dpp_mov(float x) {
  return __int_as_float(
      __builtin_amdgcn_update_dpp(0, __float_as_int(x), CTRL, 0xF, 0xF, true));
}
template <int CTRL>
__device__ __forceinline__ float dpp_add(float x) {
  return x + dpp_mov<CTRL>(x);
}
template <int XMASK>
__device__ __forceinline__ float swz_add(float x) {
  int y = __builtin_amdgcn_ds_swizzle(__float_as_int(x), (XMASK << 10) | 0x1F);
  return x + __int_as_float(y);
}
// quad_perm(1,0,3,2)=0xB1 (xor1), quad_perm(2,3,0,1)=0x4E (xor2),
// row_ror:8=0x128 (xor8 within 16), quad bcast i = {0x00,0x55,0xAA,0xFF}

constexpr float ALPHA = 0.90483741803595957f;  // exp(-1/10)
constexpr float DT    = 0.95122942450071400f;  // exp(-1/20)
constexpr float OMD   = 0.04877057549928599f;  // 1 - DT
constexpr float LR_   = 0.01f;

// ---------------- GEMM: I[m][h] = sum_k X[m][k] * W[h][k] ----------------
// M=16384, N=1024, K=256. 128x64 tile, 256 threads, 8x4 per thread.
// Known-good shape (measured 139 us round 4; 128x128 retile regressed).
template <typename T>
__global__ __launch_bounds__(256, 2) void gemm_xw(const float* __restrict__ X,
                                                  const float* __restrict__ Wm,
                                                  T* __restrict__ Out) {
  __shared__ float As[16][132];  // [k][m], pad 4
  __shared__ float Bs[16][68];   // [k][n], pad 4
  const int tid = threadIdx.x;
  const int m0 = blockIdx.x << 7;
  const int n0 = blockIdx.y << 6;
  const int tx4 = (tid & 15) << 2;
  const int ty4 = (tid >> 4) << 2;
  const int lr = tid >> 2;
  const int lk = (tid & 3) << 2;

  f32x2 acc2[8][2];
#pragma unroll
  for (int i = 0; i < 8; ++i) {
    acc2[i][0] = (f32x2){0.f, 0.f};
    acc2[i][1] = (f32x2){0.f, 0.f};
  }

  const float* xg0 = X + (size_t)(m0 + lr) * Icc + lk;
  const float* xg1 = X + (size_t)(m0 + 64 + lr) * Icc + lk;
  const float* wg  = Wm + (size_t)(n0 + lr) * Icc + lk;

  for (int k0 = 0; k0 < Icc; k0 += 16) {
    float4 a0 = *(const float4*)(xg0 + k0);
    float4 a1 = *(const float4*)(xg1 + k0);
    float4 bv = *(const float4*)(wg + k0);
    __syncthreads();
    As[lk + 0][lr] = a0.x; As[lk + 1][lr] = a0.y;
    As[lk + 2][lr] = a0.z; As[lk + 3][lr] = a0.w;
    As[lk + 0][lr + 64] = a1.x; As[lk + 1][lr + 64] = a1.y;
    As[lk + 2][lr + 64] = a1.z; As[lk + 3][lr + 64] = a1.w;
    Bs[lk + 0][lr] = bv.x; Bs[lk + 1][lr] = bv.y;
    Bs[lk + 2][lr] = bv.z; Bs[lk + 3][lr] = bv.w;
    __syncthreads();
#pragma unroll
    for (int kk = 0; kk < 16; ++kk) {
      float a[8];
      f32x2 b2[2];
      *(float4*)&a[0] = *(const float4*)&As[kk][ty4];
      *(float4*)&a[4] = *(const float4*)&As[kk][ty4 + 64];
      *(float4*)&b2[0] = *(const float4*)&Bs[kk][tx4];
#pragma unroll
      for (int i = 0; i < 8; ++i) {
        f32x2 aa = splat2(a[i]);
        acc2[i][0] += aa * b2[0];
        acc2[i][1] += aa * b2[1];
      }
    }
  }
#pragma unroll
  for (int i = 0; i < 8; ++i) {
    const int mrow = m0 + ((i < 4) ? (ty4 + i) : (64 + ty4 + i - 4));
    T* op = Out + (size_t)mrow * HW + n0 + tx4;
    if constexpr (sizeof(T) == 4) {
      *(float4*)op = make_float4(acc2[i][0].x, acc2[i][0].y, acc2[i][1].x, acc2[i][1].y);
    } else {
      stf(op + 0, acc2[i][0].x); stf(op + 1, acc2[i][0].y);
      stf(op + 2, acc2[i][1].x); stf(op + 3, acc2[i][1].y);
    }
  }
}

// ---------------- Scan (scaled-memory + chunked rescale) ----------------
// Grid (16, 64): blockIdx.y = batch, blockIdx.x = row-block (32 rows).
// 256 threads: ch = tid&31 (col chunk of 16), g = tid>>5 (row group of 4).
//
// Scaled-memory: mem(t) = A_row(t) * M~(t); update M~ += (c*invA*OMD) * K~
// -> ONE pk-fma per element pair. To bound rounding (round-6 failure:
// invA grew to ~13 over 256 steps -> matvec error amplified into vals),
// every 16 steps A_row is FOLDED into M~ and reset: invA stays <= 1.175,
// precision ~= unscaled version, amortized cost ~2.5 instr/step.
//
// kt in REGISTERS, scaled: K~ = kt/OMD obeys K~ = DT*K~ + k (one pk-fma);
// OMD folds into the broadcast c~. No kt_s LDS.
//
// Reduce-scatter butterfly (round-5-verified): lane L owns row L&3's sum;
// v-recurrence once per row; c~ broadcast back with 4 DPP movs.
// ONE barrier per step; k_s double-buffered; ik/iv prefetched a step ahead.
template <typename T>
__global__ __launch_bounds__(256, 4) void scan_kernel(const T* __restrict__ If,
                                                      float* __restrict__ mem_out,
                                                      float* __restrict__ keys,
                                                      float* __restrict__ vals) {
  const int b = blockIdx.y;
  const int rb = blockIdx.x;
  const int tid = threadIdx.x;
  const int ch = tid & 31;   // col chunk 0..31
  const int g = tid >> 5;    // row group 0..7
  const int r0 = rb << 5;
  const int row0 = r0 + (g << 2);  // first of this thread's 4 rows
  const int ri = ch & 3;           // row this lane owns after scatter

  __shared__ float k_s[2][640];    // 32 chunks x 20 floats, double-buffered

  f32x2 mem2[32];  // M~ : [i*8+jj] row row0+i, cols 16*ch + 2*jj, 2*jj+1
#pragma unroll
  for (int j = 0; j < 32; ++j) mem2[j] = (f32x2){0.f, 0.f};
  f32x2 kt2[8];    // K~ = kt/OMD for own 16 columns
#pragma unroll
  for (int j = 0; j < 8; ++j) kt2[j] = (f32x2){0.f, 0.f};
  float kss0 = 0.f, kss1 = 0.f;    // k-chain state (2 channels)
  float vs = 0.f, vt = 0.f;        // own row's v-chain
  float Arow = 1.f, invA = 1.f;    // running decay product + inverse

  const int h0 = 2 * tid;                                  // owned channels
  const int sidx = (tid >> 3) * 20 + (h0 & 15);            // staging index
  const T* ikp = If + (size_t)b * Sc * HW + h0;            // ik source
  const T* ivp = If + (size_t)b * Sc * HW + 512 + row0 + ri;  // own-row iv
  float* keysb = keys + (size_t)b * Sc * Hh;
  float* valsb = vals + (size_t)b * Sc * Hh + row0;

  const bool sb0 = (ch & 1) != 0;  // scatter-stage selects (loop-invariant)
  const bool sb1 = (ch & 2) != 0;

  // prefetch t=0 inputs
  float ik0, ik1, ivc;
  {
    if constexpr (sizeof(T) == 4) {
      float2 v2 = *(const float2*)ikp;
      ik0 = v2.x; ik1 = v2.y;
    } else {
      float2 v2 = __half22float2(*(const __half2*)ikp);
      ik0 = v2.x; ik1 = v2.y;
    }
    ivc = ldf(ivp);
  }

  for (int t = 0; t < Sc; ++t) {
    const int buf = t & 1;

    // ---- phase 1: k-chain update for own 2 channels, stage k to LDS ----
    const float cik0 = ik0, cik1 = ik1;
    const float civ = ivc;
    {  // prefetch t+1 (clamped)
      const size_t tn = (size_t)((t + 1 < Sc) ? t + 1 : t) * HW;
      if constexpr (sizeof(T) == 4) {
        float2 v2 = *(const float2*)(ikp + tn);
        ik0 = v2.x; ik1 = v2.y;
      } else {
        float2 v2 = __half22float2(*(const __half2*)(ikp + tn));
        ik0 = v2.x; ik1 = v2.y;
      }
      ivc = ldf(ivp + tn);
    }
    kss0 = ALPHA * kss0 + cik0;
    kss1 = ALPHA * kss1 + cik1;
    float k0 = fast_tanh(kss0);
    float k1 = fast_tanh(kss1);
    *(float2*)&k_s[buf][sidx] = make_float2(k0, k1);
    if (rb == 0) {
      *(float2*)&keysb[(size_t)t * Hh + h0] = make_float2(k0, k1);
    }
    __syncthreads();  // the only barrier per step

    // ---- load own 16 k values ----
    f32x2 kv2[8];
    {
      const float4* kc = (const float4*)&k_s[buf][ch * 20];
#pragma unroll
      for (int q = 0; q < 4; ++q) {
        float4 kq = kc[q];
        kv2[2 * q + 0] = (f32x2){kq.x, kq.y};
        kv2[2 * q + 1] = (f32x2){kq.z, kq.w};
      }
    }

    // ---- phase 2: matvec partials (32 pk-fma) ----
    f32x2 acc2[4];
#pragma unroll
    for (int i = 0; i < 4; ++i) acc2[i] = (f32x2){0.f, 0.f};
#pragma unroll
    for (int jj = 0; jj < 8; ++jj) {
      const f32x2 kv = kv2[jj];
      acc2[0] += mem2[jj] * kv;
      acc2[1] += mem2[8 + jj] * kv;
      acc2[2] += mem2[16 + jj] * kv;
      acc2[3] += mem2[24 + jj] * kv;
    }
    float p0 = acc2[0].x + acc2[0].y;
    float p1 = acc2[1].x + acc2[1].y;
    float p2 = acc2[2].x + acc2[2].y;
    float p3 = acc2[3].x + acc2[3].y;

    // ---- K~ trace update (8 pk-fma): K~ = DT*K~ + k ----
#pragma unroll
    for (int jj = 0; jj < 8; ++jj)
      kt2[jj] = kt2[jj] * splat2(DT) + kv2[jj];

    // ---- reduce-scatter; lane L ends with row L&3's raw sum ----
    float x  = sb0 ? p0 : p1;
    float y  = sb0 ? p2 : p3;
    float o0 = sb0 ? p1 : p0;
    float o1 = sb0 ? p3 : p2;
    float q0 = o0 + dpp_mov<0xB1>(x);
    float q1 = o1 + dpp_mov<0xB1>(y);
    float x2 = sb1 ? q0 : q1;
    float o2 = sb1 ? q1 : q0;
    float s = o2 + dpp_mov<0x4E>(x2);
    s = swz_add<4>(s);
    s = dpp_add<0x128>(s);
    s = swz_add<16>(s);
    s *= Arow;  // unscale: p_true = A_row * (M~ . k)

    // ---- phase 3: v-recurrence for the ONE owned row ----
    vs = fmaf(ALPHA, vs, fmaf(0.2f, s, civ));
    float v = fast_tanh(vs);
    vt = fmaf(DT, vt, OMD * v);
    float a_own = fmaf(-LR_ * vt, vt, 1.0f);
    float c_own = LR_ * vt;
    // scale bookkeeping: A *= a; invA *= refined rcp(a)
    Arow *= a_own;
    float r = __builtin_amdgcn_rcpf(a_own);
    r = r * fmaf(-a_own, r, 2.0f);   // Newton step
    invA *= r;
    float ct_own = c_own * invA * OMD;  // c~ (OMD folds K~ back to kt)
    if (ch < 4) {
      valsb[(size_t)t * Hh + ch] = v;  // lanes 0..3 hold rows 0..3
    }
    // broadcast c~ for all 4 rows (quad_perm bcast)
    float ct0 = dpp_mov<0x00>(ct_own), ct1 = dpp_mov<0x55>(ct_own);
    float ct2 = dpp_mov<0xAA>(ct_own), ct3 = dpp_mov<0xFF>(ct_own);

    // ---- phase 4: scaled rank-1 update (32 pk-fma): M~ += c~ * K~ ----
    {
      const f32x2 cc0 = splat2(ct0), cc1 = splat2(ct1);
      const f32x2 cc2 = splat2(ct2), cc3 = splat2(ct3);
#pragma unroll
      for (int jj = 0; jj < 8; ++jj) {
        const f32x2 kt = kt2[jj];
        mem2[jj]      += cc0 * kt;
        mem2[8 + jj]  += cc1 * kt;
        mem2[16 + jj] += cc2 * kt;
        mem2[24 + jj] += cc3 * kt;
      }
    }

    // ---- chunked rescale: every 16 steps fold A_row into M~ ----
    // Caps invA at 0.99^-16 = 1.175 so matvec rounding stays at the
    // unscaled level (round-6 precision failure fix). ~2.5 instr/step.
    if ((t & 15) == 15) {
      float f0 = dpp_mov<0x00>(Arow), f1 = dpp_mov<0x55>(Arow);
      float f2 = dpp_mov<0xAA>(Arow), f3 = dpp_mov<0xFF>(Arow);
      const f32x2 s0 = splat2(f0), s1 = splat2(f1);
      const f32x2 s2 = splat2(f2), s3 = splat2(f3);
#pragma unroll
      for (int jj = 0; jj < 8; ++jj) {
        mem2[jj]      *= s0;
        mem2[8 + jj]  *= s1;
        mem2[16 + jj] *= s2;
        mem2[24 + jj] *= s3;
      }
      Arow = 1.f;
      invA = 1.f;
    }
    // no trailing barrier: next step writes buf^1; its B1 separates this
    // step's reads of buf from step t+2's writes of buf.
  }

  // epilogue: write mem (Sc%16==0 -> last fold already applied, Arow==1)
#pragma unroll
  for (int i = 0; i < 4; ++i) {
    float* mb = mem_out + (size_t)b * Hh * Hh + (size_t)(row0 + i) * Hh + (ch << 4);
#pragma unroll
    for (int q = 0; q < 4; ++q) {
      f32x2 lo = mem2[i * 8 + 2 * q];
      f32x2 hi = mem2[i * 8 + 2 * q + 1];
      *(float4*)(mb + 4 * q) = make_float4(lo.x, lo.y, hi.x, hi.y);
    }
  }
}

extern "C" void kernel_launch(void* const* d_in, const int* in_sizes, int n_in,
                              void* d_out, int out_size, void* d_ws, size_t ws_size,
                              hipStream_t stream) {
  const float* x = (const float*)d_in[0];   // (64,256,256) fp32
  const float* W = (const float*)d_in[1];   // (1024,256) fp32
  float* out = (float*)d_out;
  float* mem_out = out;                          // 16,777,216 floats
  float* keys    = out + 16777216;               //  8,388,608 floats
  float* vals    = out + 25165824;               //  8,388,608 floats

  const dim3 gemm_grid(128, 16), gemm_blk(256);
  const dim3 scan_grid(16, 64),  scan_blk(256);
  const size_t i_elems = (size_t)Bc * Sc * HW;   // 16,777,216

  if (ws_size >= i_elems * sizeof(float)) {
    float* If = (float*)d_ws;
    gemm_xw<float><<<gemm_grid, gemm_blk, 0, stream>>>(x, W, If);
    scan_kernel<float><<<scan_grid, scan_blk, 0, stream>>>(If, mem_out, keys, vals);
  } else {
    __half* If = (__half*)d_ws;
    gemm_xw<__half><<<gemm_grid, gemm_blk, 0, stream>>>(x, W, If);
    scan_kernel<__half><<<scan_grid, scan_blk, 0, stream>>>(If, mem_out, keys, vals);
  }
}